// Round 4
// baseline (219.454 us; speedup 1.0000x reference)
//
#include <hip/hip_runtime.h>
#include <hip/hip_bf16.h>

// Shapes (fixed by the problem)
#define BATCH 8
#define SEQ   2048
#define DM    768
#define DD    64   // DK == DV == 64
#define BS (BATCH * SEQ)         // 16384
#define SCALEQ 0.1803369380478f  // (1/8) * log2(e): score in log2 domain

typedef __bf16 bf16x8 __attribute__((ext_vector_type(8)));
typedef float  f32x4  __attribute__((ext_vector_type(4)));
typedef short  short8 __attribute__((ext_vector_type(8)));
typedef short  short4v __attribute__((ext_vector_type(4)));

#define MFMA16(a, b, c) __builtin_amdgcn_mfma_f32_16x16x32_bf16((a), (b), (c), 0, 0, 0)

__device__ __forceinline__ short f2bf(float x) {
    unsigned u = __builtin_bit_cast(unsigned, x);
    u = (u + 0x7fffu + ((u >> 16) & 1u)) >> 16;   // round-to-nearest-even
    return (short)u;
}
__device__ __forceinline__ float bf2f(short s) {
    unsigned u = ((unsigned)(unsigned short)s) << 16;
    return __builtin_bit_cast(float, u);
}
__device__ __forceinline__ bf16x8 cvt8(float4 a, float4 b) {
    bf16x8 r;
    r[0] = (__bf16)a.x; r[1] = (__bf16)a.y; r[2] = (__bf16)a.z; r[3] = (__bf16)a.w;
    r[4] = (__bf16)b.x; r[5] = (__bf16)b.y; r[6] = (__bf16)b.z; r[7] = (__bf16)b.w;
    return r;
}
// async global->LDS, 16B per lane: LDS dest = wave-uniform base + lane*16;
// global src is per-lane. No VGPR result => compiler cannot "sink to use".
__device__ __forceinline__ void gload_lds16(const short* g, short* l) {
    __builtin_amdgcn_global_load_lds(
        (const __attribute__((address_space(1))) void*)g,
        (__attribute__((address_space(3))) void*)l, 16, 0, 0);
}

// ---------------------------------------------------------------------------
// Kernel 1: W [768][64] f32 -> Wt [3][64][768] bf16 (transposed, n-major).
// Wq pre-scaled by (1/8)*log2e so flash can use exp2. Zero-inits Cc.
// ---------------------------------------------------------------------------
__global__ void prep_w_kernel(const float* __restrict__ Wq, const float* __restrict__ Wk,
                              const float* __restrict__ Wv, short* __restrict__ Wt,
                              float* __restrict__ C) {
    int idx = blockIdx.x * 256 + threadIdx.x;
    if (idx < BATCH * DD) C[idx] = 0.f;
    if (idx >= 3 * DM * DD) return;
    int m = idx / (DM * DD);
    int r = (idx % (DM * DD)) / DD;
    int c = idx % DD;
    const float* W = (m == 0) ? Wq : (m == 1) ? Wk : Wv;
    float scale = (m == 0) ? SCALEQ : 1.0f;
    Wt[m * DM * DD + c * DM + r] = f2bf(W[r * DD + c] * scale);
}

// ---------------------------------------------------------------------------
// Kernel 2: projections — m97-skeleton rebuild. Rounds 1-3 proved the
// compiler sinks any single-use register load to its MFMA (VGPR 60/36,
// serialized, 69-82 us). Fix: stage W via __builtin_amdgcn_global_load_lds
// (no VGPR result -> nothing to sink; loads fly while MFMAs run), DOUBLE-
// buffered 192-k slabs, ONE barrier per phase (r0 had 8 + ds_write staging).
// 3 block types (Q/K/V) so one matrix per block: 2 x 24.6 KB LDS = 49 KB ->
// 3 blocks/CU (12 waves, vs r0's 2 blocks). x keeps r0's proven rolling
// register prefetch (depth-1, 8 loads/step in flight).
// LDS slab layout [seg s][col r][8]: stage wave w, issue i -> seg s=w*6+i,
// lane l = col l (linear dest, per-lane src = Wt row l); compute ds_read
// (b128 at s=st6*4+quad, col=wave*16+l15) hits the 8-cyc b128 floor, 0 excess
// bank conflict. x2 read by both K and V blocks (+27 MB HBM; poison fill
// flushes L3 between iters, measured r3).
// ---------------------------------------------------------------------------
#define PHK  192   // k-width per phase
#define SEGS 24    // 8-k segments per phase
__device__ __forceinline__ void stage_phase(short* dst, const short* wsrc_lane,
                                            int p, int wave) {
#pragma unroll
    for (int i = 0; i < 6; i++) {
        int s = wave * 6 + i;
        gload_lds16(wsrc_lane + p * PHK + s * 8, dst + s * 512);
    }
}

__global__ __launch_bounds__(256, 3) void proj_kernel(
        const float* __restrict__ x1, const float* __restrict__ x2,
        const short* __restrict__ Wt,
        const float* __restrict__ bq, const float* __restrict__ bk,
        const float* __restrict__ bv,
        short* __restrict__ Qs, short* __restrict__ Kb, short* __restrict__ Vtb,
        float* __restrict__ C) {
    __shared__ __align__(16) short wls[2][SEGS * 512];   // 2 x 24576 B
    const int tid = threadIdx.x, wave = tid >> 6, lane = tid & 63;
    const int quad = lane >> 4, l15 = lane & 15;
    const int typ = blockIdx.x % 3;          // 0 = Q, 1 = K, 2 = V
    const int g   = blockIdx.x / 3;          // 64-row group, 0..255
    const int r0  = g * 64;
    const float* x = (typ == 0) ? x1 : x2;
    const int col = wave * 16 + l15;

    // staging source: lane l sources W^T row l (= output col l), 16B of k
    const short* wsrc = Wt + (size_t)(typ * DD + lane) * DM;

    // x: subtile rn -> row = r0 + rn*16 + l15, k-seg quad*8
    const float* xp = x + (size_t)(r0 + l15) * DM + quad * 8;

    f32x4 acc[4] = {};
    float4 ca[4], cb[4];
#pragma unroll
    for (int rn = 0; rn < 4; rn++) {
        const float* p = xp + (size_t)(rn * 16) * DM;
        ca[rn] = *(const float4*)(p);
        cb[rn] = *(const float4*)(p + 4);
    }

    stage_phase(&wls[0][0], wsrc, 0, wave);
    __syncthreads();

#pragma unroll
    for (int p = 0; p < 4; p++) {
        if (p + 1 < 4) stage_phase(&wls[(p + 1) & 1][0], wsrc, p + 1, wave);
#pragma unroll
        for (int st6 = 0; st6 < 6; st6++) {
            const int st = p * 6 + st6;
            float4 na[4], nb[4];
            if (st + 1 < 24) {
#pragma unroll
                for (int rn = 0; rn < 4; rn++) {
                    const float* ptr = xp + (size_t)(rn * 16) * DM + (st + 1) * 32;
                    na[rn] = *(const float4*)(ptr);
                    nb[rn] = *(const float4*)(ptr + 4);
                }
            }
            bf16x8 wf = *(const bf16x8*)&wls[p & 1][(st6 * 4 + quad) * 512 + col * 8];
#pragma unroll
            for (int rn = 0; rn < 4; rn++) {
                bf16x8 af = cvt8(ca[rn], cb[rn]);
                acc[rn] = MFMA16(af, wf, acc[rn]);
            }
#pragma unroll
            for (int rn = 0; rn < 4; rn++) { ca[rn] = na[rn]; cb[rn] = nb[rn]; }
        }
        __syncthreads();   // drains stage(p+1) (landed during compute); frees buf[p&1]
    }

    if (typ == 0) {
        float bb = bq[col] * SCALEQ;
#pragma unroll
        for (int rn = 0; rn < 4; rn++)
#pragma unroll
            for (int r = 0; r < 4; r++)
                Qs[(size_t)(r0 + rn * 16 + quad * 4 + r) * DD + col] = f2bf(acc[rn][r] + bb);
    } else if (typ == 1) {
        float bb = bk[col];
#pragma unroll
        for (int rn = 0; rn < 4; rn++)
#pragma unroll
            for (int r = 0; r < 4; r++)
                Kb[(size_t)(r0 + rn * 16 + quad * 4 + r) * DD + col] = f2bf(acc[rn][r] + bb);
    } else {
        const int b  = r0 >> 11;             // row-group's batch
        const int sb = r0 & 2047;            // base s within batch
        float bb = bv[col];
        short* vout = Vtb + ((size_t)b * DD + col) * SEQ + sb;
        float cs = 0.f;
#pragma unroll
        for (int rn = 0; rn < 4; rn++) {
            short4v pk;
#pragma unroll
            for (int r = 0; r < 4; r++) {
                pk[r] = f2bf(acc[rn][r] + bb);
                cs += bf2f(pk[r]);           // sum the rounded values (consistency)
            }
            *(short4v*)(vout + rn * 16 + quad * 4) = pk;
        }
        cs += __shfl_xor(cs, 16);
        cs += __shfl_xor(cs, 32);
        if (quad == 0) atomicAdd(&C[b * DD + col], cs);
    }
}

// ---------------------------------------------------------------------------
// Kernel 3: flash partial (round-5/7 verified structure): q-tile 64, waves
// own disjoint 256-s quarters of a 1024-s half; b = blk&7 for XCD L2
// affinity. Z^T = K.Q^T (log2 domain); per-wave LDS P^T transpose; no
// main-loop barriers. Emits 2 global halves: Yp bf16 + Dp f32.
// ---------------------------------------------------------------------------
#define PBS 72   // pbuf row stride (shorts)
__global__ __launch_bounds__(256, 2) void flash_kernel(
        const short* __restrict__ Q, const short* __restrict__ K,
        const short* __restrict__ Vt,
        short* __restrict__ Yp, float* __restrict__ Dp) {
    __shared__ __align__(16) short pbuf[4][64 * PBS];  // per-wave P^T / y-partials
    __shared__ float dl[4][64];
    const int tid  = threadIdx.x;
    const int wave = tid >> 6, lane = tid & 63, quad = lane >> 4, l15 = lane & 15;
    const int blk = blockIdx.x;
    const int b = blk & 7, qt = (blk >> 3) & 31, half = blk >> 8;
    const int q0 = qt * 64;

    bf16x8 qf[4][2];
#pragma unroll
    for (int qn = 0; qn < 4; qn++)
#pragma unroll
        for (int kc = 0; kc < 2; kc++)
            qf[qn][kc] = *(const bf16x8*)(Q + ((size_t)(b * SEQ + q0 + qn * 16 + l15)) * DD
                                          + kc * 32 + quad * 8);

    const short* Kbp = K  + (size_t)b * SEQ * DD;
    const short* Vbp = Vt + (size_t)b * DD * SEQ;
    f32x4 y[4][4] = {};          // [qn][vn]
    float den[4] = {0.f, 0.f, 0.f, 0.f};
    short* pw = &pbuf[wave][0];

    const int s_begin = half * 1024 + wave * 256;
    for (int s0 = s_begin; s0 < s_begin + 256; s0 += 64) {
        // Z^T = K.Q^T  (A = K rows s, B = Q)
#pragma unroll
        for (int tn = 0; tn < 4; tn++) {
            const short* kf = Kbp + (size_t)(s0 + tn * 16 + l15) * DD + quad * 8;
            bf16x8 ka0 = *(const bf16x8*)kf;
            bf16x8 ka1 = *(const bf16x8*)(kf + 32);
#pragma unroll
            for (int qn = 0; qn < 4; qn++) {
                f32x4 z = {0.f, 0.f, 0.f, 0.f};
                z = MFMA16(ka0, qf[qn][0], z);
                z = MFMA16(ka1, qf[qn][1], z);
                short4v pk;
#pragma unroll
                for (int r = 0; r < 4; r++) {
                    float p = __builtin_amdgcn_exp2f(z[r]);
                    den[qn] += p;
                    pk[r] = f2bf(p);
                }
                *(short4v*)&pw[(qn * 16 + l15) * PBS + tn * 16 + quad * 4] = pk;
            }
        }
        // Y^T += V^T.P^T
#pragma unroll
        for (int kc = 0; kc < 2; kc++) {
            bf16x8 pB[4];
#pragma unroll
            for (int qn = 0; qn < 4; qn++)
                pB[qn] = *(const bf16x8*)&pw[(qn * 16 + l15) * PBS + kc * 32 + quad * 8];
#pragma unroll
            for (int vn = 0; vn < 4; vn++) {
                bf16x8 va = *(const bf16x8*)(Vbp + (size_t)(vn * 16 + l15) * SEQ
                                             + s0 + kc * 32 + quad * 8);
#pragma unroll
                for (int qn = 0; qn < 4; qn++)
                    y[qn][vn] = MFMA16(va, pB[qn], y[qn][vn]);
            }
        }
    }
#pragma unroll
    for (int qn = 0; qn < 4; qn++) {
        den[qn] += __shfl_xor(den[qn], 16);
        den[qn] += __shfl_xor(den[qn], 32);
    }
#pragma unroll
    for (int qn = 0; qn < 4; qn++) {
#pragma unroll
        for (int vn = 0; vn < 4; vn++) {
            short4v pk;
#pragma unroll
            for (int r = 0; r < 4; r++) pk[r] = f2bf(y[qn][vn][r]);
            *(short4v*)&pw[(qn * 16 + l15) * PBS + vn * 16 + quad * 4] = pk;
        }
        if (quad == 0) dl[wave][qn * 16 + l15] = den[qn];
    }
    __syncthreads();
    // cross-wave reduce: wave handles q = wave*16+l15; quad covers 16 v's
    {
        const int q = wave * 16 + l15;
        float D = dl[0][q] + dl[1][q] + dl[2][q] + dl[3][q];
        float ys[16];
#pragma unroll
        for (int j = 0; j < 16; j++) ys[j] = 0.f;
#pragma unroll
        for (int u = 0; u < 4; u++) {
#pragma unroll
            for (int h = 0; h < 2; h++) {
                bf16x8 t = *(const bf16x8*)&pbuf[u][q * PBS + quad * 16 + h * 8];
#pragma unroll
                for (int j = 0; j < 8; j++) ys[h * 8 + j] += (float)t[j];
            }
        }
        const size_t row = (size_t)b * SEQ + q0 + q;
        short8 o0, o1;
#pragma unroll
        for (int j = 0; j < 8; j++) { o0[j] = f2bf(ys[j]); o1[j] = f2bf(ys[8 + j]); }
        short* yout = Yp + ((size_t)half * BS + row) * DD + quad * 16;
        *(short8*)yout = o0;
        *(short8*)(yout + 8) = o1;
        if (quad == 0) Dp[half * BS + row] = D;
    }
}

// ---------------------------------------------------------------------------
// Kernel 4: combine 2 halves + reverse transform + LayerNorm. One wave/q-row.
// ---------------------------------------------------------------------------
__global__ __launch_bounds__(256) void reduce_ln_kernel(
        const short* __restrict__ Yp, const float* __restrict__ Dp,
        const float* __restrict__ C, const float* __restrict__ gamma,
        const float* __restrict__ beta, float* __restrict__ out) {
    const int row = blockIdx.x * 4 + (threadIdx.x >> 6);
    const int v = threadIdx.x & 63;
    const int b = row >> 11;
    float Y = bf2f(Yp[(size_t)row * DD + v]) + bf2f(Yp[((size_t)BS + row) * DD + v]);
    float D = Dp[row] + Dp[BS + row];
    float attn = (C[b * DD + v] - Y / D) * (1.0f / (float)(SEQ - 1));
    float msum = attn, ssum = attn * attn;
#pragma unroll
    for (int m = 1; m < 64; m <<= 1) {
        msum += __shfl_xor(msum, m);
        ssum += __shfl_xor(ssum, m);
    }
    float mu = msum * (1.0f / 64.0f);
    float var = ssum * (1.0f / 64.0f) - mu * mu;
    float rs = rsqrtf(var + 1e-5f);
    out[(size_t)row * DD + v] = (attn - mu) * rs * gamma[v] + beta[v];
}

// ---------------------------------------------------------------------------
extern "C" void kernel_launch(void* const* d_in, const int* in_sizes, int n_in,
                              void* d_out, int out_size, void* d_ws, size_t ws_size,
                              hipStream_t stream) {
    const float* x1    = (const float*)d_in[0];
    const float* x2    = (const float*)d_in[1];
    const float* Wq    = (const float*)d_in[2];
    const float* bq    = (const float*)d_in[3];
    const float* Wk    = (const float*)d_in[4];
    const float* bk    = (const float*)d_in[5];
    const float* Wv    = (const float*)d_in[6];
    const float* bv    = (const float*)d_in[7];
    const float* gamma = (const float*)d_in[8];
    const float* beta  = (const float*)d_in[9];
    float* out = (float*)d_out;

    char* ws = (char*)d_ws;
    short* Qs  = (short*)(ws);                         // 2 MB  bf16 [16384][64]
    short* Kbf = (short*)(ws + (2ull << 20));          // 2 MB  bf16 [16384][64]
    short* Vtb = (short*)(ws + (4ull << 20));          // 2 MB  bf16 [8][64][2048]
    short* Wt  = (short*)(ws + (6ull << 20));          // 288 KB bf16 [3][64][768]
    float* Cc  = (float*)(ws + (6ull << 20) + 3 * DM * DD * 2);  // 2 KB f32 [8][64]
    short* Yp  = (short*)(ws + (7ull << 20));          // 4 MB  bf16 [2][16384][64]
    float* Dp  = (float*)(ws + (11ull << 20));         // 128 KB f32 [2][16384]

    prep_w_kernel<<<576, 256, 0, stream>>>(Wq, Wk, Wv, Wt, Cc);
    proj_kernel<<<768, 256, 0, stream>>>(x1, x2, Wt, bq, bk, bv, Qs, Kbf, Vtb, Cc);
    flash_kernel<<<512, 256, 0, stream>>>(Qs, Kbf, Vtb, Yp, Dp);
    reduce_ln_kernel<<<BS / 4, 256, 0, stream>>>(Yp, Dp, Cc, gamma, beta, out);
}

// Round 5
// 181.610 us; speedup vs baseline: 1.2084x; 1.2084x over previous
//
#include <hip/hip_runtime.h>
#include <hip/hip_bf16.h>

// Shapes (fixed by the problem)
#define BATCH 8
#define SEQ   2048
#define DM    768
#define DD    64   // DK == DV == 64
#define BS (BATCH * SEQ)         // 16384
#define SCALEQ 0.1803369380478f  // (1/8) * log2(e): score in log2 domain

typedef __bf16 bf16x8 __attribute__((ext_vector_type(8)));
typedef float  f32x4  __attribute__((ext_vector_type(4)));
typedef short  short8 __attribute__((ext_vector_type(8)));
typedef short  short4v __attribute__((ext_vector_type(4)));

#define MFMA16(a, b, c) __builtin_amdgcn_mfma_f32_16x16x32_bf16((a), (b), (c), 0, 0, 0)

__device__ __forceinline__ short f2bf(float x) {
    unsigned u = __builtin_bit_cast(unsigned, x);
    u = (u + 0x7fffu + ((u >> 16) & 1u)) >> 16;   // round-to-nearest-even
    return (short)u;
}
__device__ __forceinline__ float bf2f(short s) {
    unsigned u = ((unsigned)(unsigned short)s) << 16;
    return __builtin_bit_cast(float, u);
}
__device__ __forceinline__ bf16x8 cvt8(float4 a, float4 b) {
    bf16x8 r;
    r[0] = (__bf16)a.x; r[1] = (__bf16)a.y; r[2] = (__bf16)a.z; r[3] = (__bf16)a.w;
    r[4] = (__bf16)b.x; r[5] = (__bf16)b.y; r[6] = (__bf16)b.z; r[7] = (__bf16)b.w;
    return r;
}
// async global->LDS, 16B/lane: HW writes LDS at (wave-uniform base)+lane*16;
// global src is per-lane. No VGPR result => scheduler cannot sink it to a use;
// in-flight bytes live in the DMA queue, drained only by barrier vmcnt(0).
__device__ __forceinline__ void gld16(const void* g, void* l) {
    __builtin_amdgcn_global_load_lds(
        (const __attribute__((address_space(1))) void*)g,
        (__attribute__((address_space(3))) void*)l, 16, 0, 0);
}

// ---------------------------------------------------------------------------
// Kernel 1: W [768][64] f32 -> Wt [3][64][768] bf16 (transposed, n-major).
// Wq pre-scaled by (1/8)*log2e so flash can use exp2. Zero-inits Cc.
// ---------------------------------------------------------------------------
__global__ void prep_w_kernel(const float* __restrict__ Wq, const float* __restrict__ Wk,
                              const float* __restrict__ Wv, short* __restrict__ Wt,
                              float* __restrict__ C) {
    int idx = blockIdx.x * 256 + threadIdx.x;
    if (idx < BATCH * DD) C[idx] = 0.f;
    if (idx >= 3 * DM * DD) return;
    int m = idx / (DM * DD);
    int r = (idx % (DM * DD)) / DD;
    int c = idx % DD;
    const float* W = (m == 0) ? Wq : (m == 1) ? Wk : Wv;
    float scale = (m == 0) ? SCALEQ : 1.0f;
    Wt[m * DM * DD + c * DM + r] = f2bf(W[r * DD + c] * scale);
}

// ---------------------------------------------------------------------------
// Kernel 2: projections — x-stream through global_load_lds (m97 2-barrier
// K-loop). Rounds 1-4 invariant: any global load WITH a VGPR result gets
// sunk to its MFMA use (VGPR 60/36/68; 1.5 KB/CU in flight; 69-87 us). The
// x-stream (94% of traffic) was a register load in every failed version.
// Now: per 32-k phase, stage next A-slab (64r x 32k f32 = 8 KB, 2 glds/wave)
// and next W-slab (4 KB/matrix, 1/wave) into double buffers; ds_read current
// frags; cvt->bf16; 4-8 MFMAs; ONE barrier. In-flight/CU = 8 waves x 3-4 KB
// ~= 24-32 KB >> ~9 KB Little's-law need => HBM-bound (~16 us floor), not
// latency-bound.
// A-slab both-sides swizzle (rule #21): glds writes linearly, so lane's
// SOURCE takes slot (l&7)^(row&7) and the ds_read applies the same XOR =>
// LDS[row][ds] = x[row][ds^(row&7)]; quad-group b128 reads go 16-way -> 2-way
// (free). W-slab [qseg][col][16B] layout: conflict-free (r4-measured 0).
// even blocks = Q from x1; odd = K+V from x2 (x2 staged ONCE -> ~55 MB FETCH).
// 64 rows/block, 256 threads, 32 KB LDS, 512 blocks = 2/CU.
// Accumulation k-order/rounding identical to r0 -> bit-identical outputs.
// ---------------------------------------------------------------------------
__global__ __launch_bounds__(256, 2) void proj_kernel(
        const float* __restrict__ x1, const float* __restrict__ x2,
        const short* __restrict__ Wt,
        const float* __restrict__ bq, const float* __restrict__ bk,
        const float* __restrict__ bv,
        short* __restrict__ Qs, short* __restrict__ Kb, short* __restrict__ Vtb,
        float* __restrict__ C) {
    __shared__ __align__(16) float als[2][64 * 32];   // [buf][row][32 f32]  16 KB
    __shared__ __align__(16) short wls[2][2][2048];   // [buf][mat][qseg][col][8] 16 KB
    const int tid = threadIdx.x, wave = tid >> 6, lane = tid & 63;
    const int quad = lane >> 4, l15 = lane & 15;
    const int kv = blockIdx.x & 1;             // 0 = Q, 1 = K+V
    const int r0 = (blockIdx.x >> 1) * 64;
    const float* x = kv ? x2 : x1;
    const int m0 = kv ? 1 : 0;                 // Wt matrix index (Q=0,K=1,V=2)

    // ---- staging geometry ----
    // A: issue g = wave*2 + i covers rows g*8..g*8+7 (128 B each).
    //    lane l -> row g*8 + (l>>3), source slot (l&7)^((l>>3)&7) (16B units).
    const int sg = wave * 2;
    const int arow0 = sg * 8 + (lane >> 3);
    const int aswz = ((lane & 7) ^ ((lane >> 3) & 7)) * 4;   // f32 offset
    const float* asrc0 = x + (size_t)(r0 + arow0) * DM + aswz;
    const float* asrc1 = asrc0 + (size_t)8 * DM;             // issue 1: +8 rows
    // W: issue j = wave covers qseg j; lane l -> col l, k = p*32 + j*8.
    const short* wsrc0 = Wt + (size_t)(m0 * DD + lane) * DM + wave * 8;
    const short* wsrc1 = Wt + (size_t)(2  * DD + lane) * DM + wave * 8;

    f32x4 acc0[4] = {}, acc1[4] = {};

    // prologue: stage phase 0 into buf 0
    gld16(asrc0, &als[0][sg * 256]);
    gld16(asrc1, &als[0][(sg + 1) * 256]);
    gld16(wsrc0, &wls[0][0][wave * 512]);
    if (kv) gld16(wsrc1, &wls[0][1][wave * 512]);
    __syncthreads();

    // ---- compute-side addresses ----
    const int arow = wave * 16 + l15;                        // wave owns 16 rows
    const int s0 = (((quad * 2) ^ (l15 & 7))) * 4;           // swizzled slot 0
    const int s1 = (((quad * 2 + 1) ^ (l15 & 7))) * 4;       // swizzled slot 1

    for (int p = 0; p < 24; p++) {
        const int cur = p & 1;
        if (p + 1 < 24) {
            gld16(asrc0 + (p + 1) * 32, &als[cur ^ 1][sg * 256]);
            gld16(asrc1 + (p + 1) * 32, &als[cur ^ 1][(sg + 1) * 256]);
            gld16(wsrc0 + (p + 1) * 32, &wls[cur ^ 1][0][wave * 512]);
            if (kv) gld16(wsrc1 + (p + 1) * 32, &wls[cur ^ 1][1][wave * 512]);
        }
        float4 a0 = *(const float4*)&als[cur][arow * 32 + s0];
        float4 a1 = *(const float4*)&als[cur][arow * 32 + s1];
        bf16x8 af = cvt8(a0, a1);
#pragma unroll
        for (int tn = 0; tn < 4; tn++) {
            bf16x8 w0 = *(const bf16x8*)&wls[cur][0][(quad * 64 + tn * 16 + l15) * 8];
            acc0[tn] = MFMA16(af, w0, acc0[tn]);
            if (kv) {
                bf16x8 w1 = *(const bf16x8*)&wls[cur][1][(quad * 64 + tn * 16 + l15) * 8];
                acc1[tn] = MFMA16(af, w1, acc1[tn]);
            }
        }
        __syncthreads();   // drains next-phase stages (vmcnt) + frees buf[cur]
    }

    if (!kv) {
#pragma unroll
        for (int tn = 0; tn < 4; tn++) {
            int v = tn * 16 + l15;
            float bb = bq[v] * SCALEQ;
#pragma unroll
            for (int r = 0; r < 4; r++)
                Qs[(size_t)(r0 + wave * 16 + quad * 4 + r) * DD + v] = f2bf(acc0[tn][r] + bb);
        }
    } else {
#pragma unroll
        for (int tn = 0; tn < 4; tn++) {
            int v = tn * 16 + l15;
            float bb = bk[v];
#pragma unroll
            for (int r = 0; r < 4; r++)
                Kb[(size_t)(r0 + wave * 16 + quad * 4 + r) * DD + v] = f2bf(acc0[tn][r] + bb);
        }
        const int b = r0 / SEQ;
        const int sbase = (r0 % SEQ) + wave * 16 + quad * 4;
#pragma unroll
        for (int tn = 0; tn < 4; tn++) {
            int v = tn * 16 + l15;
            float bb = bv[v];
            short4v pk;
            float cs = 0.f;
#pragma unroll
            for (int r = 0; r < 4; r++) {
                pk[r] = f2bf(acc1[tn][r] + bb);
                cs += bf2f(pk[r]);           // sum the rounded values (consistency)
            }
            *(short4v*)(Vtb + ((size_t)b * DD + v) * SEQ + sbase) = pk;
            cs += __shfl_xor(cs, 16);
            cs += __shfl_xor(cs, 32);
            if (quad == 0) atomicAdd(&C[b * DD + v], cs);
        }
    }
}

// ---------------------------------------------------------------------------
// Kernel 3: flash partial (round-5/7 verified structure): q-tile 64, waves
// own disjoint 256-s quarters of a 1024-s half; b = blk&7 for XCD L2
// affinity. Z^T = K.Q^T (log2 domain); per-wave LDS P^T transpose; no
// main-loop barriers. Emits 2 global halves: Yp bf16 + Dp f32.
// ---------------------------------------------------------------------------
#define PBS 72   // pbuf row stride (shorts)
__global__ __launch_bounds__(256, 2) void flash_kernel(
        const short* __restrict__ Q, const short* __restrict__ K,
        const short* __restrict__ Vt,
        short* __restrict__ Yp, float* __restrict__ Dp) {
    __shared__ __align__(16) short pbuf[4][64 * PBS];  // per-wave P^T / y-partials
    __shared__ float dl[4][64];
    const int tid  = threadIdx.x;
    const int wave = tid >> 6, lane = tid & 63, quad = lane >> 4, l15 = lane & 15;
    const int blk = blockIdx.x;
    const int b = blk & 7, qt = (blk >> 3) & 31, half = blk >> 8;
    const int q0 = qt * 64;

    bf16x8 qf[4][2];
#pragma unroll
    for (int qn = 0; qn < 4; qn++)
#pragma unroll
        for (int kc = 0; kc < 2; kc++)
            qf[qn][kc] = *(const bf16x8*)(Q + ((size_t)(b * SEQ + q0 + qn * 16 + l15)) * DD
                                          + kc * 32 + quad * 8);

    const short* Kbp = K  + (size_t)b * SEQ * DD;
    const short* Vbp = Vt + (size_t)b * DD * SEQ;
    f32x4 y[4][4] = {};          // [qn][vn]
    float den[4] = {0.f, 0.f, 0.f, 0.f};
    short* pw = &pbuf[wave][0];

    const int s_begin = half * 1024 + wave * 256;
    for (int s0 = s_begin; s0 < s_begin + 256; s0 += 64) {
        // Z^T = K.Q^T  (A = K rows s, B = Q)
#pragma unroll
        for (int tn = 0; tn < 4; tn++) {
            const short* kf = Kbp + (size_t)(s0 + tn * 16 + l15) * DD + quad * 8;
            bf16x8 ka0 = *(const bf16x8*)kf;
            bf16x8 ka1 = *(const bf16x8*)(kf + 32);
#pragma unroll
            for (int qn = 0; qn < 4; qn++) {
                f32x4 z = {0.f, 0.f, 0.f, 0.f};
                z = MFMA16(ka0, qf[qn][0], z);
                z = MFMA16(ka1, qf[qn][1], z);
                short4v pk;
#pragma unroll
                for (int r = 0; r < 4; r++) {
                    float p = __builtin_amdgcn_exp2f(z[r]);
                    den[qn] += p;
                    pk[r] = f2bf(p);
                }
                *(short4v*)&pw[(qn * 16 + l15) * PBS + tn * 16 + quad * 4] = pk;
            }
        }
        // Y^T += V^T.P^T
#pragma unroll
        for (int kc = 0; kc < 2; kc++) {
            bf16x8 pB[4];
#pragma unroll
            for (int qn = 0; qn < 4; qn++)
                pB[qn] = *(const bf16x8*)&pw[(qn * 16 + l15) * PBS + kc * 32 + quad * 8];
#pragma unroll
            for (int vn = 0; vn < 4; vn++) {
                bf16x8 va = *(const bf16x8*)(Vbp + (size_t)(vn * 16 + l15) * SEQ
                                             + s0 + kc * 32 + quad * 8);
#pragma unroll
                for (int qn = 0; qn < 4; qn++)
                    y[qn][vn] = MFMA16(va, pB[qn], y[qn][vn]);
            }
        }
    }
#pragma unroll
    for (int qn = 0; qn < 4; qn++) {
        den[qn] += __shfl_xor(den[qn], 16);
        den[qn] += __shfl_xor(den[qn], 32);
    }
#pragma unroll
    for (int qn = 0; qn < 4; qn++) {
#pragma unroll
        for (int vn = 0; vn < 4; vn++) {
            short4v pk;
#pragma unroll
            for (int r = 0; r < 4; r++) pk[r] = f2bf(y[qn][vn][r]);
            *(short4v*)&pw[(qn * 16 + l15) * PBS + vn * 16 + quad * 4] = pk;
        }
        if (quad == 0) dl[wave][qn * 16 + l15] = den[qn];
    }
    __syncthreads();
    // cross-wave reduce: wave handles q = wave*16+l15; quad covers 16 v's
    {
        const int q = wave * 16 + l15;
        float D = dl[0][q] + dl[1][q] + dl[2][q] + dl[3][q];
        float ys[16];
#pragma unroll
        for (int j = 0; j < 16; j++) ys[j] = 0.f;
#pragma unroll
        for (int u = 0; u < 4; u++) {
#pragma unroll
            for (int h = 0; h < 2; h++) {
                bf16x8 t = *(const bf16x8*)&pbuf[u][q * PBS + quad * 16 + h * 8];
#pragma unroll
                for (int j = 0; j < 8; j++) ys[h * 8 + j] += (float)t[j];
            }
        }
        const size_t row = (size_t)b * SEQ + q0 + q;
        short8 o0, o1;
#pragma unroll
        for (int j = 0; j < 8; j++) { o0[j] = f2bf(ys[j]); o1[j] = f2bf(ys[8 + j]); }
        short* yout = Yp + ((size_t)half * BS + row) * DD + quad * 16;
        *(short8*)yout = o0;
        *(short8*)(yout + 8) = o1;
        if (quad == 0) Dp[half * BS + row] = D;
    }
}

// ---------------------------------------------------------------------------
// Kernel 4: combine 2 halves + reverse transform + LayerNorm. One wave/q-row.
// ---------------------------------------------------------------------------
__global__ __launch_bounds__(256) void reduce_ln_kernel(
        const short* __restrict__ Yp, const float* __restrict__ Dp,
        const float* __restrict__ C, const float* __restrict__ gamma,
        const float* __restrict__ beta, float* __restrict__ out) {
    const int row = blockIdx.x * 4 + (threadIdx.x >> 6);
    const int v = threadIdx.x & 63;
    const int b = row >> 11;
    float Y = bf2f(Yp[(size_t)row * DD + v]) + bf2f(Yp[((size_t)BS + row) * DD + v]);
    float D = Dp[row] + Dp[BS + row];
    float attn = (C[b * DD + v] - Y / D) * (1.0f / (float)(SEQ - 1));
    float msum = attn, ssum = attn * attn;
#pragma unroll
    for (int m = 1; m < 64; m <<= 1) {
        msum += __shfl_xor(msum, m);
        ssum += __shfl_xor(ssum, m);
    }
    float mu = msum * (1.0f / 64.0f);
    float var = ssum * (1.0f / 64.0f) - mu * mu;
    float rs = rsqrtf(var + 1e-5f);
    out[(size_t)row * DD + v] = (attn - mu) * rs * gamma[v] + beta[v];
}

// ---------------------------------------------------------------------------
extern "C" void kernel_launch(void* const* d_in, const int* in_sizes, int n_in,
                              void* d_out, int out_size, void* d_ws, size_t ws_size,
                              hipStream_t stream) {
    const float* x1    = (const float*)d_in[0];
    const float* x2    = (const float*)d_in[1];
    const float* Wq    = (const float*)d_in[2];
    const float* bq    = (const float*)d_in[3];
    const float* Wk    = (const float*)d_in[4];
    const float* bk    = (const float*)d_in[5];
    const float* Wv    = (const float*)d_in[6];
    const float* bv    = (const float*)d_in[7];
    const float* gamma = (const float*)d_in[8];
    const float* beta  = (const float*)d_in[9];
    float* out = (float*)d_out;

    char* ws = (char*)d_ws;
    short* Qs  = (short*)(ws);                         // 2 MB  bf16 [16384][64]
    short* Kbf = (short*)(ws + (2ull << 20));          // 2 MB  bf16 [16384][64]
    short* Vtb = (short*)(ws + (4ull << 20));          // 2 MB  bf16 [8][64][2048]
    short* Wt  = (short*)(ws + (6ull << 20));          // 288 KB bf16 [3][64][768]
    float* Cc  = (float*)(ws + (6ull << 20) + 3 * DM * DD * 2);  // 2 KB f32 [8][64]
    short* Yp  = (short*)(ws + (7ull << 20));          // 4 MB  bf16 [2][16384][64]
    float* Dp  = (float*)(ws + (11ull << 20));         // 128 KB f32 [2][16384]

    prep_w_kernel<<<576, 256, 0, stream>>>(Wq, Wk, Wv, Wt, Cc);
    proj_kernel<<<512, 256, 0, stream>>>(x1, x2, Wt, bq, bk, bv, Qs, Kbf, Vtb, Cc);
    flash_kernel<<<512, 256, 0, stream>>>(Qs, Kbf, Vtb, Yp, Dp);
    reduce_ln_kernel<<<BS / 4, 256, 0, stream>>>(Yp, Dp, Cc, gamma, beta, out);
}

// Round 6
// 178.806 us; speedup vs baseline: 1.2273x; 1.0157x over previous
//
#include <hip/hip_runtime.h>
#include <hip/hip_bf16.h>

// Shapes (fixed by the problem)
#define BATCH 8
#define SEQ   2048
#define DM    768
#define DD    64   // DK == DV == 64
#define BS (BATCH * SEQ)         // 16384
#define SCALEQ 0.1803369380478f  // (1/8) * log2(e): score in log2 domain

typedef __bf16 bf16x8 __attribute__((ext_vector_type(8)));
typedef float  f32x4  __attribute__((ext_vector_type(4)));
typedef short  short8 __attribute__((ext_vector_type(8)));
typedef short  short4v __attribute__((ext_vector_type(4)));

#define MFMA16(a, b, c) __builtin_amdgcn_mfma_f32_16x16x32_bf16((a), (b), (c), 0, 0, 0)

__device__ __forceinline__ short f2bf(float x) {
    unsigned u = __builtin_bit_cast(unsigned, x);
    u = (u + 0x7fffu + ((u >> 16) & 1u)) >> 16;   // round-to-nearest-even
    return (short)u;
}
__device__ __forceinline__ float bf2f(short s) {
    unsigned u = ((unsigned)(unsigned short)s) << 16;
    return __builtin_bit_cast(float, u);
}
__device__ __forceinline__ bf16x8 cvt8(float4 a, float4 b) {
    bf16x8 r;
    r[0] = (__bf16)a.x; r[1] = (__bf16)a.y; r[2] = (__bf16)a.z; r[3] = (__bf16)a.w;
    r[4] = (__bf16)b.x; r[5] = (__bf16)b.y; r[6] = (__bf16)b.z; r[7] = (__bf16)b.w;
    return r;
}
// async global->LDS, 16B/lane: HW writes LDS at (wave-uniform base)+lane*16;
// global src is per-lane. No VGPR result => scheduler cannot sink it to a use;
// in-flight bytes live in the DMA queue, tracked by vmcnt in issue order.
__device__ __forceinline__ void gld16(const void* g, void* l) {
    __builtin_amdgcn_global_load_lds(
        (const __attribute__((address_space(1))) void*)g,
        (__attribute__((address_space(3))) void*)l, 16, 0, 0);
}

// ---------------------------------------------------------------------------
// Kernel 1: W [768][64] f32 -> Wt [3][64][768] bf16 (transposed, n-major).
// Wq pre-scaled by (1/8)*log2e so flash can use exp2. Zero-inits Cc.
// ---------------------------------------------------------------------------
__global__ void prep_w_kernel(const float* __restrict__ Wq, const float* __restrict__ Wk,
                              const float* __restrict__ Wv, short* __restrict__ Wt,
                              float* __restrict__ C) {
    int idx = blockIdx.x * 256 + threadIdx.x;
    if (idx < BATCH * DD) C[idx] = 0.f;
    if (idx >= 3 * DM * DD) return;
    int m = idx / (DM * DD);
    int r = (idx % (DM * DD)) / DD;
    int c = idx % DD;
    const float* W = (m == 0) ? Wq : (m == 1) ? Wk : Wv;
    float scale = (m == 0) ? SCALEQ : 1.0f;
    Wt[m * DM * DD + c * DM + r] = f2bf(W[r * DD + c] * scale);
}

// ---------------------------------------------------------------------------
// Kernel 2: projections — COUNTED-vmcnt depth-3 glds pipeline (T4/m218).
// r5 (glds + __syncthreads per phase, 48.7 us) still drained vmcnt(0) every
// phase: depth-0 synchronous, full ~900-cyc HBM latency exposed per 32-k
// phase. Now: 4 LDS buffers, prologue stages phases 0-2; each phase issues
// stage(p+3), waits s_waitcnt vmcnt(3G) (G=glds/wave/phase; vmcnt retires
// in issue order -> <=3G outstanding == phase p landed), raw s_barrier,
// compute, raw s_barrier (read-before-overwrite fence: stage(p+4) targets
// buf[p&3]). NEVER vmcnt(0) in the loop; epilogue peels 2G/G/0.
// sched_barrier(0) after each wait (rule #18). Geometry/swizzle/k-order
// identical to r5 -> bit-identical outputs.
// even blocks = Q from x1 (G=3: 2 A-glds + 1 W); odd = K+V from x2 (G=4).
// 64 rows/block, 256 threads, 64 KB LDS, 512 blocks = 2/CU.
// ---------------------------------------------------------------------------
__global__ __launch_bounds__(256, 2) void proj_kernel(
        const float* __restrict__ x1, const float* __restrict__ x2,
        const short* __restrict__ Wt,
        const float* __restrict__ bq, const float* __restrict__ bk,
        const float* __restrict__ bv,
        short* __restrict__ Qs, short* __restrict__ Kb, short* __restrict__ Vtb,
        float* __restrict__ C) {
    __shared__ __align__(16) float als[4][64 * 32];   // [buf][row][32 f32]  32 KB
    __shared__ __align__(16) short wls[4][2][2048];   // [buf][mat][qseg][col][8] 32 KB
    const int tid = threadIdx.x, wave = tid >> 6, lane = tid & 63;
    const int quad = lane >> 4, l15 = lane & 15;
    const int kv = blockIdx.x & 1;             // 0 = Q, 1 = K+V
    const int r0 = (blockIdx.x >> 1) * 64;
    const float* x = kv ? x2 : x1;
    const int m0 = kv ? 1 : 0;                 // Wt matrix index (Q=0,K=1,V=2)

    // ---- staging geometry (identical to r5) ----
    const int sg = wave * 2;
    const int arow0 = sg * 8 + (lane >> 3);
    const int aswz = ((lane & 7) ^ ((lane >> 3) & 7)) * 4;   // f32 offset
    const float* asrc0 = x + (size_t)(r0 + arow0) * DM + aswz;
    const float* asrc1 = asrc0 + (size_t)8 * DM;             // +8 rows
    const short* wsrc0 = Wt + (size_t)(m0 * DD + lane) * DM + wave * 8;
    const short* wsrc1 = Wt + (size_t)(2  * DD + lane) * DM + wave * 8;

    f32x4 acc0[4] = {}, acc1[4] = {};

    // ---- compute-side addresses ----
    const int arow = wave * 16 + l15;
    const int s0 = ((quad * 2) ^ (l15 & 7)) * 4;
    const int s1 = ((quad * 2 + 1) ^ (l15 & 7)) * 4;

#define PROJ_WAIT(N)                                         \
    asm volatile("s_waitcnt vmcnt(" #N ")" ::: "memory");    \
    __builtin_amdgcn_sched_barrier(0);                       \
    __builtin_amdgcn_s_barrier();

    if (!kv) {
        auto STAGE = [&](int t) {
            float* ab = &als[t & 3][0];
            gld16(asrc0 + t * 32, ab + sg * 256);
            gld16(asrc1 + t * 32, ab + (sg + 1) * 256);
            gld16(wsrc0 + t * 32, &wls[t & 3][0][wave * 512]);
        };
        auto COMP = [&](int p) {
            const float* ab = &als[p & 3][0];
            float4 a0 = *(const float4*)(ab + arow * 32 + s0);
            float4 a1 = *(const float4*)(ab + arow * 32 + s1);
            bf16x8 af = cvt8(a0, a1);
            const short* wb = &wls[p & 3][0][0];
#pragma unroll
            for (int tn = 0; tn < 4; tn++)
                acc0[tn] = MFMA16(af, *(const bf16x8*)(wb + (quad * 64 + tn * 16 + l15) * 8),
                                  acc0[tn]);
        };
        STAGE(0); STAGE(1); STAGE(2);
        for (int p = 0; p < 21; ++p) {
            STAGE(p + 3);
            PROJ_WAIT(9)              // 3G: phases p+1..p+3 in flight, p landed
            COMP(p);
            __builtin_amdgcn_s_barrier();   // reads done before buf[p&3] reuse
        }
        PROJ_WAIT(6)  COMP(21); __builtin_amdgcn_s_barrier();
        PROJ_WAIT(3)  COMP(22); __builtin_amdgcn_s_barrier();
        PROJ_WAIT(0)  COMP(23);
#pragma unroll
        for (int tn = 0; tn < 4; tn++) {
            int v = tn * 16 + l15;
            float bb = bq[v] * SCALEQ;
#pragma unroll
            for (int r = 0; r < 4; r++)
                Qs[(size_t)(r0 + wave * 16 + quad * 4 + r) * DD + v] = f2bf(acc0[tn][r] + bb);
        }
    } else {
        auto STAGE = [&](int t) {
            float* ab = &als[t & 3][0];
            gld16(asrc0 + t * 32, ab + sg * 256);
            gld16(asrc1 + t * 32, ab + (sg + 1) * 256);
            gld16(wsrc0 + t * 32, &wls[t & 3][0][wave * 512]);
            gld16(wsrc1 + t * 32, &wls[t & 3][1][wave * 512]);
        };
        auto COMP = [&](int p) {
            const float* ab = &als[p & 3][0];
            float4 a0 = *(const float4*)(ab + arow * 32 + s0);
            float4 a1 = *(const float4*)(ab + arow * 32 + s1);
            bf16x8 af = cvt8(a0, a1);
            const short* wb0 = &wls[p & 3][0][0];
            const short* wb1 = &wls[p & 3][1][0];
#pragma unroll
            for (int tn = 0; tn < 4; tn++) {
                const int fo = (quad * 64 + tn * 16 + l15) * 8;
                acc0[tn] = MFMA16(af, *(const bf16x8*)(wb0 + fo), acc0[tn]);
                acc1[tn] = MFMA16(af, *(const bf16x8*)(wb1 + fo), acc1[tn]);
            }
        };
        STAGE(0); STAGE(1); STAGE(2);
        for (int p = 0; p < 21; ++p) {
            STAGE(p + 3);
            PROJ_WAIT(12)
            COMP(p);
            __builtin_amdgcn_s_barrier();
        }
        PROJ_WAIT(8)  COMP(21); __builtin_amdgcn_s_barrier();
        PROJ_WAIT(4)  COMP(22); __builtin_amdgcn_s_barrier();
        PROJ_WAIT(0)  COMP(23);
#pragma unroll
        for (int tn = 0; tn < 4; tn++) {
            int v = tn * 16 + l15;
            float bb = bk[v];
#pragma unroll
            for (int r = 0; r < 4; r++)
                Kb[(size_t)(r0 + wave * 16 + quad * 4 + r) * DD + v] = f2bf(acc0[tn][r] + bb);
        }
        const int b = r0 / SEQ;
        const int sbase = (r0 % SEQ) + wave * 16 + quad * 4;
#pragma unroll
        for (int tn = 0; tn < 4; tn++) {
            int v = tn * 16 + l15;
            float bb = bv[v];
            short4v pk;
            float cs = 0.f;
#pragma unroll
            for (int r = 0; r < 4; r++) {
                pk[r] = f2bf(acc1[tn][r] + bb);
                cs += bf2f(pk[r]);           // sum the rounded values (consistency)
            }
            *(short4v*)(Vtb + ((size_t)b * DD + v) * SEQ + sbase) = pk;
            cs += __shfl_xor(cs, 16);
            cs += __shfl_xor(cs, 32);
            if (quad == 0) atomicAdd(&C[b * DD + v], cs);
        }
    }
#undef PROJ_WAIT
}

// ---------------------------------------------------------------------------
// Kernel 3: flash partial (round-5/7 verified structure): q-tile 64, waves
// own disjoint 256-s quarters of a 1024-s half; b = blk&7 for XCD L2
// affinity. Z^T = K.Q^T (log2 domain); per-wave LDS P^T transpose; no
// main-loop barriers. Emits 2 global halves: Yp bf16 + Dp f32.
// ---------------------------------------------------------------------------
#define PBS 72   // pbuf row stride (shorts)
__global__ __launch_bounds__(256, 2) void flash_kernel(
        const short* __restrict__ Q, const short* __restrict__ K,
        const short* __restrict__ Vt,
        short* __restrict__ Yp, float* __restrict__ Dp) {
    __shared__ __align__(16) short pbuf[4][64 * PBS];  // per-wave P^T / y-partials
    __shared__ float dl[4][64];
    const int tid  = threadIdx.x;
    const int wave = tid >> 6, lane = tid & 63, quad = lane >> 4, l15 = lane & 15;
    const int blk = blockIdx.x;
    const int b = blk & 7, qt = (blk >> 3) & 31, half = blk >> 8;
    const int q0 = qt * 64;

    bf16x8 qf[4][2];
#pragma unroll
    for (int qn = 0; qn < 4; qn++)
#pragma unroll
        for (int kc = 0; kc < 2; kc++)
            qf[qn][kc] = *(const bf16x8*)(Q + ((size_t)(b * SEQ + q0 + qn * 16 + l15)) * DD
                                          + kc * 32 + quad * 8);

    const short* Kbp = K  + (size_t)b * SEQ * DD;
    const short* Vbp = Vt + (size_t)b * DD * SEQ;
    f32x4 y[4][4] = {};          // [qn][vn]
    float den[4] = {0.f, 0.f, 0.f, 0.f};
    short* pw = &pbuf[wave][0];

    const int s_begin = half * 1024 + wave * 256;
    for (int s0 = s_begin; s0 < s_begin + 256; s0 += 64) {
        // Z^T = K.Q^T  (A = K rows s, B = Q)
#pragma unroll
        for (int tn = 0; tn < 4; tn++) {
            const short* kf = Kbp + (size_t)(s0 + tn * 16 + l15) * DD + quad * 8;
            bf16x8 ka0 = *(const bf16x8*)kf;
            bf16x8 ka1 = *(const bf16x8*)(kf + 32);
#pragma unroll
            for (int qn = 0; qn < 4; qn++) {
                f32x4 z = {0.f, 0.f, 0.f, 0.f};
                z = MFMA16(ka0, qf[qn][0], z);
                z = MFMA16(ka1, qf[qn][1], z);
                short4v pk;
#pragma unroll
                for (int r = 0; r < 4; r++) {
                    float p = __builtin_amdgcn_exp2f(z[r]);
                    den[qn] += p;
                    pk[r] = f2bf(p);
                }
                *(short4v*)&pw[(qn * 16 + l15) * PBS + tn * 16 + quad * 4] = pk;
            }
        }
        // Y^T += V^T.P^T
#pragma unroll
        for (int kc = 0; kc < 2; kc++) {
            bf16x8 pB[4];
#pragma unroll
            for (int qn = 0; qn < 4; qn++)
                pB[qn] = *(const bf16x8*)&pw[(qn * 16 + l15) * PBS + kc * 32 + quad * 8];
#pragma unroll
            for (int vn = 0; vn < 4; vn++) {
                bf16x8 va = *(const bf16x8*)(Vbp + (size_t)(vn * 16 + l15) * SEQ
                                             + s0 + kc * 32 + quad * 8);
#pragma unroll
                for (int qn = 0; qn < 4; qn++)
                    y[qn][vn] = MFMA16(va, pB[qn], y[qn][vn]);
            }
        }
    }
#pragma unroll
    for (int qn = 0; qn < 4; qn++) {
        den[qn] += __shfl_xor(den[qn], 16);
        den[qn] += __shfl_xor(den[qn], 32);
    }
#pragma unroll
    for (int qn = 0; qn < 4; qn++) {
#pragma unroll
        for (int vn = 0; vn < 4; vn++) {
            short4v pk;
#pragma unroll
            for (int r = 0; r < 4; r++) pk[r] = f2bf(y[qn][vn][r]);
            *(short4v*)&pw[(qn * 16 + l15) * PBS + vn * 16 + quad * 4] = pk;
        }
        if (quad == 0) dl[wave][qn * 16 + l15] = den[qn];
    }
    __syncthreads();
    // cross-wave reduce: wave handles q = wave*16+l15; quad covers 16 v's
    {
        const int q = wave * 16 + l15;
        float D = dl[0][q] + dl[1][q] + dl[2][q] + dl[3][q];
        float ys[16];
#pragma unroll
        for (int j = 0; j < 16; j++) ys[j] = 0.f;
#pragma unroll
        for (int u = 0; u < 4; u++) {
#pragma unroll
            for (int h = 0; h < 2; h++) {
                bf16x8 t = *(const bf16x8*)&pbuf[u][q * PBS + quad * 16 + h * 8];
#pragma unroll
                for (int j = 0; j < 8; j++) ys[h * 8 + j] += (float)t[j];
            }
        }
        const size_t row = (size_t)b * SEQ + q0 + q;
        short8 o0, o1;
#pragma unroll
        for (int j = 0; j < 8; j++) { o0[j] = f2bf(ys[j]); o1[j] = f2bf(ys[8 + j]); }
        short* yout = Yp + ((size_t)half * BS + row) * DD + quad * 16;
        *(short8*)yout = o0;
        *(short8*)(yout + 8) = o1;
        if (quad == 0) Dp[half * BS + row] = D;
    }
}

// ---------------------------------------------------------------------------
// Kernel 4: combine 2 halves + reverse transform + LayerNorm. One wave/q-row.
// ---------------------------------------------------------------------------
__global__ __launch_bounds__(256) void reduce_ln_kernel(
        const short* __restrict__ Yp, const float* __restrict__ Dp,
        const float* __restrict__ C, const float* __restrict__ gamma,
        const float* __restrict__ beta, float* __restrict__ out) {
    const int row = blockIdx.x * 4 + (threadIdx.x >> 6);
    const int v = threadIdx.x & 63;
    const int b = row >> 11;
    float Y = bf2f(Yp[(size_t)row * DD + v]) + bf2f(Yp[((size_t)BS + row) * DD + v]);
    float D = Dp[row] + Dp[BS + row];
    float attn = (C[b * DD + v] - Y / D) * (1.0f / (float)(SEQ - 1));
    float msum = attn, ssum = attn * attn;
#pragma unroll
    for (int m = 1; m < 64; m <<= 1) {
        msum += __shfl_xor(msum, m);
        ssum += __shfl_xor(ssum, m);
    }
    float mu = msum * (1.0f / 64.0f);
    float var = ssum * (1.0f / 64.0f) - mu * mu;
    float rs = rsqrtf(var + 1e-5f);
    out[(size_t)row * DD + v] = (attn - mu) * rs * gamma[v] + beta[v];
}

// ---------------------------------------------------------------------------
extern "C" void kernel_launch(void* const* d_in, const int* in_sizes, int n_in,
                              void* d_out, int out_size, void* d_ws, size_t ws_size,
                              hipStream_t stream) {
    const float* x1    = (const float*)d_in[0];
    const float* x2    = (const float*)d_in[1];
    const float* Wq    = (const float*)d_in[2];
    const float* bq    = (const float*)d_in[3];
    const float* Wk    = (const float*)d_in[4];
    const float* bk    = (const float*)d_in[5];
    const float* Wv    = (const float*)d_in[6];
    const float* bv    = (const float*)d_in[7];
    const float* gamma = (const float*)d_in[8];
    const float* beta  = (const float*)d_in[9];
    float* out = (float*)d_out;

    char* ws = (char*)d_ws;
    short* Qs  = (short*)(ws);                         // 2 MB  bf16 [16384][64]
    short* Kbf = (short*)(ws + (2ull << 20));          // 2 MB  bf16 [16384][64]
    short* Vtb = (short*)(ws + (4ull << 20));          // 2 MB  bf16 [8][64][2048]
    short* Wt  = (short*)(ws + (6ull << 20));          // 288 KB bf16 [3][64][768]
    float* Cc  = (float*)(ws + (6ull << 20) + 3 * DM * DD * 2);  // 2 KB f32 [8][64]
    short* Yp  = (short*)(ws + (7ull << 20));          // 4 MB  bf16 [2][16384][64]
    float* Dp  = (float*)(ws + (11ull << 20));         // 128 KB f32 [2][16384]

    prep_w_kernel<<<576, 256, 0, stream>>>(Wq, Wk, Wv, Wt, Cc);
    proj_kernel<<<512, 256, 0, stream>>>(x1, x2, Wt, bq, bk, bv, Qs, Kbf, Vtb, Cc);
    flash_kernel<<<512, 256, 0, stream>>>(Qs, Kbf, Vtb, Yp, Dp);
    reduce_ln_kernel<<<BS / 4, 256, 0, stream>>>(Yp, Dp, Cc, gamma, beta, out);
}